// Round 8
// baseline (248.865 us; speedup 1.0000x reference)
//
#include <hip/hip_runtime.h>
#include <stdint.h>

#define BATCH 32
#define NH    32
#define KVH   8
#define QPK   4
#define DH    128
#define BS    128
#define NEG   (-1e30f)
#define SCALEF 0.08838834764831845f  // 1/sqrt(128)
#define MAXU  64
#define NSP   4          // token-split WGs per (seq, kv-head)
#define CHK   16         // tokens per wave per block
#define KVROW (KVH * DH)

#define GAS __attribute__((address_space(1)))
#define LAS __attribute__((address_space(3)))

// R5 structure + counted waits + padded q_lds, with the V double-buffer kept
// STATIC (named arrays via 2x-unrolled macro bodies -- no runtime selection,
// which in R7 spilled vA/vB to scratch: 264MB writes, +150MB reads).
// Body order: vmcnt(9) [K(cur) done; V(cur)+ab(cur) = 9 newest still fly] ->
// stage K(next) -> QK(cur) -> load V(next)+ab(next) -> softmax (ab_c counted
// wait) -> AV (V(cur) counted wait). No wait ever drains the prefetch.

#define STAGE_K(PB, BUFI) do {                                                  \
  const float* kbase_ = key_cache + ((size_t)(PB) * BS + T0) * KVROW + g * DH;  \
  float* dst_ = &Kbuf[w][BUFI][0];                                              \
  _Pragma("unroll")                                                             \
  for (int seg = 0; seg < 8; ++seg) {                                           \
    const int t_  = 2 * seg + half;                                             \
    const int sg_ = r32 ^ t_;                                                   \
    __builtin_amdgcn_global_load_lds(                                           \
        (const GAS void*)(kbase_ + (size_t)t_ * KVROW + sg_ * 4),               \
        (LAS void*)(dst_ + seg * 256), 16, 0, 0);                               \
  }                                                                             \
} while (0)

#define LOAD_V(PB, VR) do {                                                     \
  const float* vb_ = value_cache + ((size_t)(PB) * BS + T0 + half) * KVROW      \
                   + g * DH + r32 * 4;                                          \
  _Pragma("unroll")                                                             \
  for (int tp = 0; tp < 8; ++tp)                                                \
    VR[tp] = *(const float4*)&vb_[(size_t)tp * 2 * KVROW];                      \
} while (0)

#define BODY(CIDX, BUFC, BUFN, VCUR, VNXT) do {                                 \
  __builtin_amdgcn_sched_barrier(0);                                            \
  asm volatile("s_waitcnt vmcnt(9)" ::: "memory");                              \
  __builtin_amdgcn_sched_barrier(0);                                            \
  const bool hn_ = (CIDX) + 1 < nblk;                                           \
  int u_n_ = 0, pb_n_ = 0, us_n_ = 0;                                           \
  if (hn_) {                                                                    \
    u_n_ = ulist[(CIDX) + 1]; pb_n_ = pblds[(CIDX) + 1];                        \
    us_n_ = uslds[(CIDX) + 1];                                                  \
    STAGE_K(pb_n_, BUFN);                                                       \
  }                                                                             \
  __builtin_amdgcn_sched_barrier(0);                                            \
  /* QK from Kbuf[w][BUFC] (swizzled K, padded q: both conflict-clean) */       \
  float a0_ = 0.f, a1_ = 0.f, a2_ = 0.f, a3_ = 0.f;                             \
  {                                                                             \
    const float* kb_ = &Kbuf[w][BUFC][0];                                       \
    _Pragma("unroll")                                                           \
    for (int i = 0; i < 8; ++i) {                                               \
      const int pos_ = (dq * 8 + i) ^ r16;                                      \
      const float4 kv = *(const float4*)&kb_[r16 * DH + pos_ * 4];              \
      const float4 q0 = *(const float4*)&q_lds[((0 * 4 + dq) * 9 + i) * 4];     \
      const float4 q1 = *(const float4*)&q_lds[((1 * 4 + dq) * 9 + i) * 4];     \
      const float4 q2 = *(const float4*)&q_lds[((2 * 4 + dq) * 9 + i) * 4];     \
      const float4 q3 = *(const float4*)&q_lds[((3 * 4 + dq) * 9 + i) * 4];     \
      a0_ += kv.x*q0.x + kv.y*q0.y + kv.z*q0.z + kv.w*q0.w;                     \
      a1_ += kv.x*q1.x + kv.y*q1.y + kv.z*q1.z + kv.w*q1.w;                     \
      a2_ += kv.x*q2.x + kv.y*q2.y + kv.z*q2.z + kv.w*q2.w;                     \
      a3_ += kv.x*q3.x + kv.y*q3.y + kv.z*q3.z + kv.w*q3.w;                     \
    }                                                                           \
  }                                                                             \
  /* V(next)+ab(next) issued after K(next): 9 newest at next body top */        \
  float ab_n_ = 0.f;                                                            \
  if (hn_) {                                                                    \
    LOAD_V(pb_n_, VNXT);                                                        \
    ab_n_ = alibi_blocks[(size_t)u_n_ * BS + T0 + r16];                         \
  }                                                                             \
  /* online softmax over this wave's 16 tokens (uses ab_c, us_c) */             \
  {                                                                             \
    float accv_[QPK] = {a0_, a1_, a2_, a3_};                                    \
    const bool valid_ = (T0 + r16) < us_c;                                      \
    float pr_[QPK];                                                             \
    _Pragma("unroll")                                                           \
    for (int qh = 0; qh < QPK; ++qh) {                                          \
      float sc = accv_[qh] + __shfl_xor(accv_[qh], 16);                         \
      sc += __shfl_xor(sc, 32);                                                 \
      sc += ab_c * slope[qh];                                                   \
      if (!valid_) sc = NEG;                                                    \
      float cm = sc;                                                            \
      _Pragma("unroll")                                                         \
      for (int off = 1; off < 16; off <<= 1)                                    \
        cm = fmaxf(cm, __shfl_xor(cm, off));                                    \
      const float mnew = fmaxf(m[qh], cm);                                      \
      const float rs   = __expf(m[qh] - mnew);                                  \
      m[qh] = mnew;                                                             \
      pr_[qh] = valid_ ? __expf(sc - mnew) : 0.f;                               \
      sacc[qh] = sacc[qh] * rs + ((lane < 16) ? pr_[qh] : 0.f);                 \
      O[qh][0] *= rs; O[qh][1] *= rs; O[qh][2] *= rs; O[qh][3] *= rs;           \
    }                                                                           \
    if (lane < 16)                                                              \
      *(float4*)&p_lds[w][r16 * 4] =                                            \
          make_float4(pr_[0], pr_[1], pr_[2], pr_[3]);                          \
  }                                                                             \
  /* AV from VCUR (compiler inserts counted wait for VCUR's loads) */           \
  _Pragma("unroll")                                                             \
  for (int tp = 0; tp < 8; ++tp) {                                              \
    const float4 pv = *(const float4*)&p_lds[w][(2 * tp + half) * 4];           \
    const float4 vv = VCUR[tp];                                                 \
    O[0][0]+=pv.x*vv.x; O[0][1]+=pv.x*vv.y; O[0][2]+=pv.x*vv.z; O[0][3]+=pv.x*vv.w; \
    O[1][0]+=pv.y*vv.x; O[1][1]+=pv.y*vv.y; O[1][2]+=pv.y*vv.z; O[1][3]+=pv.y*vv.w; \
    O[2][0]+=pv.z*vv.x; O[2][1]+=pv.z*vv.y; O[2][2]+=pv.z*vv.z; O[2][3]+=pv.z*vv.w; \
    O[3][0]+=pv.w*vv.x; O[3][1]+=pv.w*vv.y; O[3][2]+=pv.w*vv.z; O[3][3]+=pv.w*vv.w; \
  }                                                                             \
  us_c = us_n_; ab_c = ab_n_;                                                   \
} while (0)

__global__ __launch_bounds__(128, 2)
void pa_partial(const float* __restrict__ query,
                const float* __restrict__ key_cache,
                const float* __restrict__ value_cache,
                const float* __restrict__ alibi_blocks,
                const float* __restrict__ alibi_slopes,
                const int* __restrict__ block_list,
                const int* __restrict__ block_groups,
                const int* __restrict__ block_usage,
                float* __restrict__ Mp, float* __restrict__ Sp,
                float* __restrict__ Op, int U) {
  __shared__ __align__(16) float Kbuf[2][2][CHK * DH];   // 32 KiB per-wave dbuf
  __shared__ __align__(16) float q_lds[QPK * 4 * 9 * 4]; // padded, 2.25 KiB
  __shared__ __align__(16) float p_lds[2][CHK * QPK];    // 512 B
  __shared__ int ulist[MAXU], pblds[MAXU], uslds[MAXU];
  __shared__ int ucount;

  const int tid  = threadIdx.x;
  const int w    = tid >> 6;
  const int lane = tid & 63;
  const int r32  = lane & 31;   // V/stage: d-granule
  const int half = lane >> 5;   // V/stage: token parity
  const int r16  = lane & 15;   // QK: token within chunk
  const int dq   = lane >> 4;   // QK: d-quarter
  const int bid  = blockIdx.x;
  const int b    = bid >> 5;    // / (KVH*NSP)
  const int g    = (bid >> 2) & 7;
  const int s    = bid & 3;
  const int T0   = s * 32 + w * CHK;   // this wave's token slice in each block

  // ---- gather this sequence's block entries (order-preserving) ----
  if (w == 0) {
    int cnt = 0;
    for (int base = 0; base < U; base += 64) {
      const int u = base + lane;
      const bool match = (u < U) && (block_groups[u] == b);
      const unsigned long long mk = __ballot(match);
      if (match) {
        const int pre = __popcll(mk & ((1ull << lane) - 1ull));
        if (cnt + pre < MAXU) ulist[cnt + pre] = u;
      }
      cnt += __popcll(mk);
    }
    if (cnt > MAXU) cnt = MAXU;
    if (lane == 0) ucount = cnt;
    for (int i = lane; i < cnt; i += 64) {
      const int u = ulist[i];
      pblds[i] = block_list[u];
      uslds[i] = block_usage[u];
    }
  }

  // ---- scaled query -> padded LDS: q_lds[((qh*4+dq)*9 + i)*4 + k] ----
  {
    const float* qsrc = query + ((size_t)b * NH + g * QPK) * DH;
    for (int e = tid; e < QPK * DH; e += 128) {
      const int qh = e >> 7, idx = e & 127;
      const int qq = idx >> 5, ii = (idx >> 2) & 7, kk = idx & 3;
      q_lds[((qh * 4 + qq) * 9 + ii) * 4 + kk] = qsrc[e] * SCALEF;
    }
  }

  float slope[QPK];
#pragma unroll
  for (int qh = 0; qh < QPK; ++qh) slope[qh] = alibi_slopes[g * QPK + qh];

  __syncthreads();  // metadata + q visible (vmcnt drained here, before loop)

  const int nblk = ucount;

  float m[QPK], sacc[QPK], O[QPK][4];
#pragma unroll
  for (int qh = 0; qh < QPK; ++qh) {
    m[qh] = NEG; sacc[qh] = 0.f;
#pragma unroll
    for (int k = 0; k < 4; ++k) O[qh][k] = 0.f;
  }

  float4 vA[8], vB[8];
  int us_c = 0;
  float ab_c = 0.f;

  if (nblk > 0) {  // prologue: K(0) first (8 issues), then V(0)+ab(0) (9)
    const int u0 = ulist[0], pb0 = pblds[0];
    us_c = uslds[0];
    STAGE_K(pb0, 0);
    __builtin_amdgcn_sched_barrier(0);
    LOAD_V(pb0, vA);
    ab_c = alibi_blocks[(size_t)u0 * BS + T0 + r16];
  }

  for (int c = 0; c < nblk; c += 2) {
    BODY(c, 0, 1, vA, vB);
    if (c + 1 < nblk) BODY(c + 1, 1, 0, vB, vA);
  }

  // ---- per-wave finalize into own (now dead) Kbuf slice ----
  float* cO  = &Kbuf[w][0][0];   // [qh*DH + d]
  float* cMS = &Kbuf[w][1][0];   // [qh]=M, [4+qh]=S
#pragma unroll
  for (int qh = 0; qh < QPK; ++qh) {
    float sv = sacc[qh];
#pragma unroll
    for (int off = 1; off < 64; off <<= 1) sv += __shfl_xor(sv, off);
#pragma unroll
    for (int k = 0; k < 4; ++k) O[qh][k] += __shfl_xor(O[qh][k], 32);
    if (half == 0) {
#pragma unroll
      for (int k = 0; k < 4; ++k) cO[qh * DH + r32 * 4 + k] = O[qh][k];
    }
    if (lane == 0) { cMS[qh] = m[qh]; cMS[4 + qh] = sv; }
  }
  __syncthreads();

  // ---- cross-wave (2) flash combine -> partial (M,S,O) to workspace ----
  for (int e = tid; e < QPK * DH; e += 128) {
    const int qh = e >> 7, d = e & 127;
    const float M  = fmaxf(Kbuf[0][1][qh], Kbuf[1][1][qh]);
    const float f0 = __expf(Kbuf[0][1][qh] - M);
    const float f1 = __expf(Kbuf[1][1][qh] - M);
    const float S  = f0 * Kbuf[0][1][4 + qh] + f1 * Kbuf[1][1][4 + qh];
    const float Ov = f0 * Kbuf[0][0][qh * DH + d] + f1 * Kbuf[1][0][qh * DH + d];
    const int P = ((b * KVH + g) * QPK + qh) * NSP + s;
    Op[(size_t)P * DH + d] = Ov;
    if (d == 0) { Mp[P] = M; Sp[P] = S; }
  }
}

// Combine the NSP partials per (b, head, d).
__global__ __launch_bounds__(256, 1)
void pa_combine(const float* __restrict__ Mp, const float* __restrict__ Sp,
                const float* __restrict__ Op, float* __restrict__ out) {
  const int e  = blockIdx.x * 256 + threadIdx.x;   // b*4096 + h*128 + d
  const int d  = e & 127;
  const int h  = (e >> 7) & 31;
  const int bb = e >> 12;
  const int gg = h >> 2, qh = h & 3;
  const int P  = ((bb * KVH + gg) * QPK + qh) * NSP;
  float M = NEG;
#pragma unroll
  for (int sp = 0; sp < NSP; ++sp) M = fmaxf(M, Mp[P + sp]);
  float S = 0.f, Ov = 0.f;
#pragma unroll
  for (int sp = 0; sp < NSP; ++sp) {
    const float f = __expf(Mp[P + sp] - M);
    S  += f * Sp[P + sp];
    Ov += f * Op[(size_t)(P + sp) * DH + d];
  }
  out[e] = Ov / S;
}

extern "C" void kernel_launch(void* const* d_in, const int* in_sizes, int n_in,
                              void* d_out, int out_size, void* d_ws, size_t ws_size,
                              hipStream_t stream) {
  (void)n_in; (void)out_size; (void)ws_size;
  const float* query        = (const float*)d_in[0];
  const float* key_cache    = (const float*)d_in[1];
  const float* value_cache  = (const float*)d_in[2];
  const float* alibi_blocks = (const float*)d_in[3];
  const float* alibi_slopes = (const float*)d_in[4];
  const int*   block_list   = (const int*)d_in[5];
  const int*   block_groups = (const int*)d_in[6];
  const int*   block_usage  = (const int*)d_in[7];
  float*       out          = (float*)d_out;
  const int U = in_sizes[5];

  const int NP = BATCH * KVH * QPK * NSP;          // 4096 partials
  float* Mp = (float*)d_ws;
  float* Sp = Mp + NP;
  float* Op = Sp + NP;

  pa_partial<<<dim3(BATCH * KVH * NSP), dim3(128), 0, stream>>>(
      query, key_cache, value_cache, alibi_blocks, alibi_slopes,
      block_list, block_groups, block_usage, Mp, Sp, Op, U);

  pa_combine<<<dim3(BATCH * NH * DH / 256), dim3(256), 0, stream>>>(Mp, Sp, Op, out);
}

// Round 9
// 105.821 us; speedup vs baseline: 2.3517x; 2.3517x over previous
//
#include <hip/hip_runtime.h>
#include <stdint.h>

#define BATCH 32
#define NH    32
#define KVH   8
#define QPK   4
#define DH    128
#define BS    128
#define NEG   (-1e30f)
#define SCALEF 0.08838834764831845f  // 1/sqrt(128)
#define MAXU  64
#define NSP   4          // token-split WGs per (seq, kv-head)
#define CHK   16         // tokens per wave per block
#define KVROW (KVH * DH)

#define GAS __attribute__((address_space(1)))
#define LAS __attribute__((address_space(3)))

// R5 structure with a SINGLE V register buffer reloaded AFTER its last use
// (AV), giving a full-iteration V/ab prefetch with no double-buffer state
// (R7/R8's vA/vB ping-pong spilled to scratch: 143-264MB of HBM writes).
// Body: vmcnt(9) [retires exactly K(cur); V(cur)+ab(cur) = 9 newest still
// in flight] -> stage K(next) -> QK(cur) -> softmax (compiler-counted wait
// on ab) -> AV (vreg) -> reload vreg=V(next), ab=ab(next). No wait in the
// loop ever drains the K prefetch or waits on anything < 1 iteration old.
__global__ __launch_bounds__(128, 2)
void pa_partial(const float* __restrict__ query,
                const float* __restrict__ key_cache,
                const float* __restrict__ value_cache,
                const float* __restrict__ alibi_blocks,
                const float* __restrict__ alibi_slopes,
                const int* __restrict__ block_list,
                const int* __restrict__ block_groups,
                const int* __restrict__ block_usage,
                float* __restrict__ Mp, float* __restrict__ Sp,
                float* __restrict__ Op, int U) {
  __shared__ __align__(16) float Kbuf[2][2][CHK * DH];   // 32 KiB per-wave dbuf
  __shared__ __align__(16) float q_lds[QPK * 4 * 9 * 4]; // padded, 2.25 KiB
  __shared__ __align__(16) float p_lds[2][CHK * QPK];    // 512 B
  __shared__ int ulist[MAXU], pblds[MAXU], uslds[MAXU];
  __shared__ int ucount;

  const int tid  = threadIdx.x;
  const int w    = tid >> 6;
  const int lane = tid & 63;
  const int r32  = lane & 31;   // V/stage: d-granule
  const int half = lane >> 5;   // V/stage: token parity
  const int r16  = lane & 15;   // QK: token within chunk
  const int dq   = lane >> 4;   // QK: d-quarter
  const int bid  = blockIdx.x;
  const int b    = bid >> 5;    // / (KVH*NSP)
  const int g    = (bid >> 2) & 7;
  const int s    = bid & 3;
  const int T0   = s * 32 + w * CHK;   // this wave's token slice in each block

  // ---- gather this sequence's block entries (order-preserving) ----
  if (w == 0) {
    int cnt = 0;
    for (int base = 0; base < U; base += 64) {
      const int u = base + lane;
      const bool match = (u < U) && (block_groups[u] == b);
      const unsigned long long mk = __ballot(match);
      if (match) {
        const int pre = __popcll(mk & ((1ull << lane) - 1ull));
        if (cnt + pre < MAXU) ulist[cnt + pre] = u;
      }
      cnt += __popcll(mk);
    }
    if (cnt > MAXU) cnt = MAXU;
    if (lane == 0) ucount = cnt;
    for (int i = lane; i < cnt; i += 64) {
      const int u = ulist[i];
      pblds[i] = block_list[u];
      uslds[i] = block_usage[u];
    }
  }

  // ---- scaled query -> padded LDS: q_lds[((qh*4+dq)*9 + i)*4 + k] ----
  // dq groups land in 4 distinct bank groups (granule step 9 = 1 mod 8),
  // so QK's 4-address broadcast reads are conflict-free.
  {
    const float* qsrc = query + ((size_t)b * NH + g * QPK) * DH;
    for (int e = tid; e < QPK * DH; e += 128) {
      const int qh = e >> 7, idx = e & 127;
      const int qq = idx >> 5, ii = (idx >> 2) & 7, kk = idx & 3;
      q_lds[((qh * 4 + qq) * 9 + ii) * 4 + kk] = qsrc[e] * SCALEF;
    }
  }

  float slope[QPK];
#pragma unroll
  for (int qh = 0; qh < QPK; ++qh) slope[qh] = alibi_slopes[g * QPK + qh];

  __syncthreads();  // metadata + q visible (drains vmcnt before the loop)

  const int nblk = ucount;

  float m[QPK], sacc[QPK], O[QPK][4];
#pragma unroll
  for (int qh = 0; qh < QPK; ++qh) {
    m[qh] = NEG; sacc[qh] = 0.f;
#pragma unroll
    for (int k = 0; k < 4; ++k) O[qh][k] = 0.f;
  }

  float4 vreg[8];          // SINGLE buffer: holds V(cur); reloaded after AV
  int   us_c = 0;
  float ab_c = 0.f;
  int   cur  = 0;

  if (nblk > 0) {  // prologue: K(0) FIRST (8 ops), then V(0)+ab(0) (9 ops)
    const int u0 = ulist[0], pb0 = pblds[0];
    us_c = uslds[0];
    {
      const float* kbase = key_cache + ((size_t)pb0 * BS + T0) * KVROW + g * DH;
      float* dst = &Kbuf[w][0][0];
#pragma unroll
      for (int seg = 0; seg < 8; ++seg) {
        const int t  = 2 * seg + half;
        const int sg = r32 ^ t;
        __builtin_amdgcn_global_load_lds((const GAS void*)(kbase + (size_t)t * KVROW + sg * 4),
                                         (LAS void*)(dst + seg * 256), 16, 0, 0);
      }
    }
    __builtin_amdgcn_sched_barrier(0);   // pin order: K before V (FIFO count)
    {
      const float* vb = value_cache + ((size_t)pb0 * BS + T0 + half) * KVROW
                      + g * DH + r32 * 4;
#pragma unroll
      for (int tp = 0; tp < 8; ++tp)
        vreg[tp] = *(const float4*)&vb[(size_t)tp * 2 * KVROW];
      ab_c = alibi_blocks[(size_t)u0 * BS + T0 + r16];
    }
  }

  for (int c = 0; c < nblk; ++c) {
    // ---- top: retire exactly K(cur); V(cur)+ab(cur) (9 newest) keep flying ----
    __builtin_amdgcn_sched_barrier(0);
    asm volatile("s_waitcnt vmcnt(9)" ::: "memory");
    __builtin_amdgcn_sched_barrier(0);

    const bool has_nxt = (c + 1 < nblk);
    int u_n = 0, pb_n = 0, us_n = 0;
    if (has_nxt) { u_n = ulist[c + 1]; pb_n = pblds[c + 1]; us_n = uslds[c + 1]; }

    // ---- (1) stage K(next) ----
    if (has_nxt) {
      const float* kbase = key_cache + ((size_t)pb_n * BS + T0) * KVROW + g * DH;
      float* dst = &Kbuf[w][cur ^ 1][0];
#pragma unroll
      for (int seg = 0; seg < 8; ++seg) {
        const int t  = 2 * seg + half;
        const int sg = r32 ^ t;
        __builtin_amdgcn_global_load_lds((const GAS void*)(kbase + (size_t)t * KVROW + sg * 4),
                                         (LAS void*)(dst + seg * 256), 16, 0, 0);
      }
    }
    __builtin_amdgcn_sched_barrier(0);

    // ---- (2) QK from Kbuf[w][cur] (swizzled K + padded q: conflict-free) ----
    const float* kb = &Kbuf[w][cur][0];
    float acc[QPK] = {0.f, 0.f, 0.f, 0.f};
#pragma unroll
    for (int i = 0; i < 8; ++i) {
      const int pos = (dq * 8 + i) ^ r16;            // swizzled LDS slot
      const float4 kv = *(const float4*)&kb[r16 * DH + pos * 4];
#pragma unroll
      for (int qh = 0; qh < QPK; ++qh) {
        const float4 qv = *(const float4*)&q_lds[((qh * 4 + dq) * 9 + i) * 4];
        acc[qh] += kv.x * qv.x + kv.y * qv.y + kv.z * qv.z + kv.w * qv.w;
      }
    }

    // ---- (3) online softmax (ab_c: compiler-counted wait, keeps K(next)) ----
    const bool valid = (T0 + r16) < us_c;
    float p[QPK];
#pragma unroll
    for (int qh = 0; qh < QPK; ++qh) {
      float sc = acc[qh] + __shfl_xor(acc[qh], 16);   // sum d-quarters
      sc += __shfl_xor(sc, 32);
      sc += ab_c * slope[qh];
      if (!valid) sc = NEG;
      float cm = sc;
#pragma unroll
      for (int off = 1; off < 16; off <<= 1) cm = fmaxf(cm, __shfl_xor(cm, off));
      const float mnew = fmaxf(m[qh], cm);
      const float rs   = __expf(m[qh] - mnew);
      m[qh] = mnew;
      p[qh] = valid ? __expf(sc - mnew) : 0.f;
      sacc[qh] = sacc[qh] * rs + ((lane < 16) ? p[qh] : 0.f);
#pragma unroll
      for (int k = 0; k < 4; ++k) O[qh][k] *= rs;
    }
    if (lane < 16)
      *(float4*)&p_lds[w][r16 * 4] = make_float4(p[0], p[1], p[2], p[3]);

    // ---- (4) AV from vreg = V(cur) (already retired by softmax's wait) ----
#pragma unroll
    for (int tp = 0; tp < 8; ++tp) {
      const float4 pv = *(const float4*)&p_lds[w][(2 * tp + half) * 4];
      const float4 vv = vreg[tp];
      O[0][0]+=pv.x*vv.x; O[0][1]+=pv.x*vv.y; O[0][2]+=pv.x*vv.z; O[0][3]+=pv.x*vv.w;
      O[1][0]+=pv.y*vv.x; O[1][1]+=pv.y*vv.y; O[1][2]+=pv.y*vv.z; O[1][3]+=pv.y*vv.w;
      O[2][0]+=pv.z*vv.x; O[2][1]+=pv.z*vv.y; O[2][2]+=pv.z*vv.z; O[2][3]+=pv.z*vv.w;
      O[3][0]+=pv.w*vv.x; O[3][1]+=pv.w*vv.y; O[3][2]+=pv.w*vv.z; O[3][3]+=pv.w*vv.w;
    }

    // ---- (5) reload vreg = V(next), ab = ab(next) (after vreg's last use) ----
    if (has_nxt) {
      const float* vb = value_cache + ((size_t)pb_n * BS + T0 + half) * KVROW
                      + g * DH + r32 * 4;
#pragma unroll
      for (int tp = 0; tp < 8; ++tp)
        vreg[tp] = *(const float4*)&vb[(size_t)tp * 2 * KVROW];
      ab_c = alibi_blocks[(size_t)u_n * BS + T0 + r16];
      us_c = us_n;
    }
    cur ^= 1;
  }

  // ---- per-wave finalize into own (now dead) Kbuf slice ----
  float* cO  = &Kbuf[w][0][0];   // [qh*DH + d]
  float* cMS = &Kbuf[w][1][0];   // [qh]=M, [4+qh]=S
#pragma unroll
  for (int qh = 0; qh < QPK; ++qh) {
    float sv = sacc[qh];
#pragma unroll
    for (int off = 1; off < 64; off <<= 1) sv += __shfl_xor(sv, off);
#pragma unroll
    for (int k = 0; k < 4; ++k) O[qh][k] += __shfl_xor(O[qh][k], 32);
    if (half == 0) {
#pragma unroll
      for (int k = 0; k < 4; ++k) cO[qh * DH + r32 * 4 + k] = O[qh][k];
    }
    if (lane == 0) { cMS[qh] = m[qh]; cMS[4 + qh] = sv; }
  }
  __syncthreads();

  // ---- cross-wave (2) flash combine -> partial (M,S,O) to workspace ----
  for (int e = tid; e < QPK * DH; e += 128) {
    const int qh = e >> 7, d = e & 127;
    const float M  = fmaxf(Kbuf[0][1][qh], Kbuf[1][1][qh]);
    const float f0 = __expf(Kbuf[0][1][qh] - M);
    const float f1 = __expf(Kbuf[1][1][qh] - M);
    const float S  = f0 * Kbuf[0][1][4 + qh] + f1 * Kbuf[1][1][4 + qh];
    const float Ov = f0 * Kbuf[0][0][qh * DH + d] + f1 * Kbuf[1][0][qh * DH + d];
    const int P = ((b * KVH + g) * QPK + qh) * NSP + s;
    Op[(size_t)P * DH + d] = Ov;
    if (d == 0) { Mp[P] = M; Sp[P] = S; }
  }
}

// Combine the NSP partials per (b, head, d).
__global__ __launch_bounds__(256, 1)
void pa_combine(const float* __restrict__ Mp, const float* __restrict__ Sp,
                const float* __restrict__ Op, float* __restrict__ out) {
  const int e  = blockIdx.x * 256 + threadIdx.x;   // b*4096 + h*128 + d
  const int d  = e & 127;
  const int h  = (e >> 7) & 31;
  const int bb = e >> 12;
  const int gg = h >> 2, qh = h & 3;
  const int P  = ((bb * KVH + gg) * QPK + qh) * NSP;
  float M = NEG;
#pragma unroll
  for (int sp = 0; sp < NSP; ++sp) M = fmaxf(M, Mp[P + sp]);
  float S = 0.f, Ov = 0.f;
#pragma unroll
  for (int sp = 0; sp < NSP; ++sp) {
    const float f = __expf(Mp[P + sp] - M);
    S  += f * Sp[P + sp];
    Ov += f * Op[(size_t)(P + sp) * DH + d];
  }
  out[e] = Ov / S;
}

extern "C" void kernel_launch(void* const* d_in, const int* in_sizes, int n_in,
                              void* d_out, int out_size, void* d_ws, size_t ws_size,
                              hipStream_t stream) {
  (void)n_in; (void)out_size; (void)ws_size;
  const float* query        = (const float*)d_in[0];
  const float* key_cache    = (const float*)d_in[1];
  const float* value_cache  = (const float*)d_in[2];
  const float* alibi_blocks = (const float*)d_in[3];
  const float* alibi_slopes = (const float*)d_in[4];
  const int*   block_list   = (const int*)d_in[5];
  const int*   block_groups = (const int*)d_in[6];
  const int*   block_usage  = (const int*)d_in[7];
  float*       out          = (float*)d_out;
  const int U = in_sizes[5];

  const int NP = BATCH * KVH * QPK * NSP;          // 4096 partials
  float* Mp = (float*)d_ws;
  float* Sp = Mp + NP;
  float* Op = Sp + NP;

  pa_partial<<<dim3(BATCH * KVH * NSP), dim3(128), 0, stream>>>(
      query, key_cache, value_cache, alibi_blocks, alibi_slopes,
      block_list, block_groups, block_usage, Mp, Sp, Op, U);

  pa_combine<<<dim3(BATCH * NH * DH / 256), dim3(256), 0, stream>>>(Mp, Sp, Op, out);
}